// Round 4
// baseline (130.161 us; speedup 1.0000x reference)
//
#include <hip/hip_runtime.h>
#include <cstdint>

// ---------------- problem constants ----------------
static constexpr int RPI    = 256;   // ROIS_PER_IMAGE
static constexpr int MAXPOS = 64;    // round(256*0.25)
static constexpr int MAX_GT = 256;   // LDS capacity for gt boxes (M=200)
static constexpr int MAXG   = 4096;  // max 64-ROI groups

// ---------------- workspace layout (bytes) ----------------
static constexpr size_t WS_CNT    = 0;                                  // int, zeroed per launch
static constexpr size_t WS_GRPPOS = 64;
static constexpr size_t WS_GRPNEG = WS_GRPPOS + (size_t)MAXG * 4;
static constexpr size_t WS_BESTGT = WS_GRPNEG + (size_t)MAXG * 4;       // int16 per ROI
static constexpr size_t WS_KEY    = WS_BESTGT + (size_t)262144 * 2;     // uint8 per ROI

// One fused kernel. Block = 256 thr = 4 waves, owns 128 ROIs (2/lane);
// waves j-split-4 over GTs staged in LDS (32B-aligned interleaved layout ->
// single base + immediate-offset ds_read_b128/b32, unroll-5 pipelines them).
// Rational argmax tracking (bi, c1): r_c > r_b  <=>  I_c*c1_b > bi_b*S_c,
// ONE IEEE divide per ROI on an exactly-recomputed (ref op order) value.
// Last block (threadfence + atomicAdd on ws counter) runs scan/select/emit.
__global__ __launch_bounds__(256, 6) void ptl_fused(
    const float* __restrict__ rois, const float* __restrict__ gts,
    const int* __restrict__ labels, int N, int M,
    uint8_t* __restrict__ key, int16_t* __restrict__ bestgt,
    int* __restrict__ grpPos, int* __restrict__ grpNeg,
    int* __restrict__ cnt,
    float* __restrict__ outD, float* __restrict__ outH, int ngroups)
{
#pragma clang fp contract(off)
    __shared__ float4 sg4[2 * MAX_GT];        // [2j]=box, [2j+1]=(area+eps, area, -, -)
    __shared__ float  sbi[4][128], sc1[4][128];
    __shared__ short  sbj[4][128];
    __shared__ int    slot[RPI], slab[RPI];
    __shared__ int    redP[4], redN[4];
    __shared__ int    s_last, s_tp, s_tn;

    const int tid = threadIdx.x;
    const int w = tid >> 6, l = tid & 63;

    // ---- stage GTs ----
    for (int j = tid; j < M; j += 256) {
        float4 g = ((const float4*)gts)[j];
        float a = (g.z - g.x) * (g.w - g.y);          // ref op order
        sg4[2 * j]     = g;
        sg4[2 * j + 1] = make_float4(a + 1e-7f, a, 0.f, 0.f);
    }
    __syncthreads();

    // ---- main IoU loop ----
    const int base = blockIdx.x * 128;
    const int r0 = base + l, r1 = r0 + 64;
    const float4 zb = make_float4(0.f, 0.f, 0.f, 0.f);
    float4 b0 = (r0 < N) ? ((const float4*)rois)[r0] : zb;
    float4 b1 = (r1 < N) ? ((const float4*)rois)[r1] : zb;
    float aA0 = (b0.z - b0.x) * (b0.w - b0.y);
    float aA1 = (b1.z - b1.x) * (b1.w - b1.y);

    const int seglen = (M + 3) >> 2;
    const int j0 = w * seglen, j1 = min(M, j0 + seglen);

    float bi0 = -1.f, c10 = 0.f, bi1 = -1.f, c11 = 0.f;   // first j always wins
    int   bj0 = j0,   bj1 = j0;
#pragma unroll 5
    for (int j = j0; j < j1; ++j) {
        float4 g   = sg4[2 * j];
        float  abe = sg4[2 * j + 1].x;
        {
            float ih = fmaxf(fminf(b0.z, g.z) - fmaxf(b0.x, g.x), 0.f);
            float iw = fmaxf(fminf(b0.w, g.w) - fmaxf(b0.y, g.y), 0.f);
            float inter = ih * iw;
            float S = aA0 + abe;
            bool  s = (inter * c10) > (bi0 * S);
            bi0 = s ? inter : bi0;  c10 = s ? S : c10;  bj0 = s ? j : bj0;
        }
        {
            float ih = fmaxf(fminf(b1.z, g.z) - fmaxf(b1.x, g.x), 0.f);
            float iw = fmaxf(fminf(b1.w, g.w) - fmaxf(b1.y, g.y), 0.f);
            float inter = ih * iw;
            float S = aA1 + abe;
            bool  s = (inter * c11) > (bi1 * S);
            bi1 = s ? inter : bi1;  c11 = s ? S : c11;  bj1 = s ? j : bj1;
        }
    }
    sbi[w][l]      = bi0;  sc1[w][l]      = c10;  sbj[w][l]      = (short)bj0;
    sbi[w][64 + l] = bi1;  sc1[w][64 + l] = c11;  sbj[w][64 + l] = (short)bj1;
    __syncthreads();

    // ---- merge segment partials (order keeps first-occurrence argmax) ----
    if (tid < 128) {
        float BI = sbi[0][tid], C1 = sc1[0][tid];
        int   BJ = (int)sbj[0][tid];
#pragma unroll
        for (int s2 = 1; s2 < 4; ++s2) {
            float ci = sbi[s2][tid], cc = sc1[s2][tid];
            bool sel = (ci * C1) > (BI * cc);
            BI = sel ? ci : BI;  C1 = sel ? cc : C1;
            BJ = sel ? (int)sbj[s2][tid] : BJ;
        }
        // thread tid<64 holds b0 for ROI base+tid; tid in [64,128) holds b1
        // for ROI base+64+(tid-64) == base+tid (verified passing in R3).
        float4 bb = (tid < 64) ? b0 : b1;
        float  aa = (tid < 64) ? aA0 : aA1;
        int r = base + tid;
        int kk = 2;
        if (r < N) {
            float4 g  = sg4[2 * BJ];
            float  ab = sg4[2 * BJ + 1].y;
            float ih = fmaxf(fminf(bb.z, g.z) - fmaxf(bb.x, g.x), 0.f);
            float iw = fmaxf(fminf(bb.w, g.w) - fmaxf(bb.y, g.y), 0.f);
            float inter = ih * iw;
            float u1 = ((aa + ab) - inter) + 1e-7f;   // exact ref op order
            float q  = inter / u1;                    // the ONLY division
            kk = (q > 0.5f) ? 0 : ((q < 0.5f && q > 0.1f) ? 1 : 2);
            key[r]    = (uint8_t)kk;
            bestgt[r] = (int16_t)BJ;
        }
        unsigned long long mp = __ballot(kk == 0);
        unsigned long long mn = __ballot(kk == 1);
        if (l == 0) {
            grpPos[blockIdx.x * 2 + w] = __popcll(mp);
            grpNeg[blockIdx.x * 2 + w] = __popcll(mn);
        }
    }

    // ---- last-block handoff (device-scope release/acquire) ----
    __threadfence();                       // each thread's global writes visible
    __syncthreads();                       // all fences done before the atomic
    if (tid == 0) s_last = (atomicAdd(cnt, 1) == (int)gridDim.x - 1);
    __syncthreads();
    if (!s_last) return;
    __threadfence();                       // acquire: see all other blocks' data

    // ---- totals ----
    int sumP = 0, sumN = 0;
    for (int g = tid; g < ngroups; g += 256) { sumP += grpPos[g]; sumN += grpNeg[g]; }
#pragma unroll
    for (int o = 32; o > 0; o >>= 1) {
        sumP += __shfl_down(sumP, o);
        sumN += __shfl_down(sumN, o);
    }
    if (l == 0) { redP[w] = sumP; redN[w] = sumN; }
    if (tid < RPI) slot[tid] = -1;
    __syncthreads();
    if (tid == 0) {
        int totP = redP[0] + redP[1] + redP[2] + redP[3];
        int totN = redN[0] + redN[1] + redN[2] + redN[3];
        int tp  = totP < MAXPOS ? totP : MAXPOS;
        int rem = RPI - tp;
        s_tp = tp;
        s_tn = totN < rem ? totN : rem;
    }
    __syncthreads();
    const int tp = s_tp, tn = s_tn;

    // ---- select: wave 0 walks groups in order, prefetching next group ----
    if (w == 0) {
        int g = 0, cp = 0, cn = 0;
        int kc = (l < N) ? (int)key[l] : 2;           // group 0 prefetched
        while (g < ngroups && (cp < tp || cn < tn)) {
            int gn = g + 1;
            int i2 = gn * 64 + l;
            int kn = (gn < ngroups && i2 < N) ? (int)key[i2] : 2;
            unsigned long long mp = __ballot(kc == 0);
            unsigned long long mn = __ballot(kc == 1);
            unsigned long long lt = (1ull << l) - 1ull;
            int i = g * 64 + l;
            if (kc == 0) {
                int rr = cp + __popcll(mp & lt);
                if (rr < tp) slot[rr] = i;
            } else if (kc == 1) {
                int rr = cn + __popcll(mn & lt);
                if (rr < tn) slot[tp + rr] = i;
            }
            cp += __popcll(mp); cn += __popcll(mn);
            kc = kn; g = gn;
        }
    }
    __syncthreads();

    // ---- emit: deltas + label per row (256 threads = 256 rows) ----
    {
        int  roi   = slot[tid];
        bool valid = roi >= 0;
        bool ispos = valid && (tid < tp);
        float d0 = 0.f, d1 = 0.f, d2 = 0.f, d3 = 0.f;
        int lab = valid ? 0 : -1;                     // -1 => all-zero one-hot row
        if (ispos) {
            int gi    = (int)bestgt[roi];
            float4 b  = ((const float4*)rois)[roi];
            float4 gb = sg4[2 * gi];                  // GT boxes still staged
            lab = labels[gi];
            float bh  = b.z - b.x,  bw  = b.w - b.y;
            float bcy = b.x + 0.5f * bh, bcx = b.y + 0.5f * bw;
            float gh  = gb.z - gb.x, gw  = gb.w - gb.y;
            float gcy = gb.x + 0.5f * gh, gcx = gb.y + 0.5f * gw;
            float bhs = (bh == 0.f) ? 1.f : bh;
            float bws = (bw == 0.f) ? 1.f : bw;
            float ghs = (gh <= 0.f) ? 1.f : gh;
            float gws = (gw <= 0.f) ? 1.f : gw;
            float dy = (gh == 0.f) ? 0.f : (gcy - bcy) / bhs;
            float dx = (gw == 0.f) ? 0.f : (gcx - bcx) / bws;
            float dh = (gh == 0.f) ? 0.f : logf(ghs / bhs);
            float dw = (gw == 0.f) ? 0.f : logf(gws / bws);
            d0 = dy / 0.1f; d1 = dx / 0.1f; d2 = dh / 0.2f; d3 = dw / 0.2f;
        }
        slab[tid] = lab;
        ((float4*)outD)[tid] = make_float4(d0, d1, d2, d3);
    }
    __syncthreads();

    // ---- one-hot: coalesced, div-free index walk (256*91 / 256 = 91 iters) ----
    {
        int rr = tid / 91, cc = tid - rr * 91;
        for (int it = 0; it < 91; ++it) {
            outH[rr * 91 + cc] = (cc == slab[rr]) ? 1.0f : 0.0f;
            cc += 74; rr += 2;                        // += 256 elements
            if (cc >= 91) { cc -= 91; ++rr; }
        }
    }
}

// ---------------- host launcher ----------------
extern "C" void kernel_launch(void* const* d_in, const int* in_sizes, int n_in,
                              void* d_out, int out_size, void* d_ws, size_t ws_size,
                              hipStream_t stream) {
    const float* rois   = (const float*)d_in[1];   // [1,N,4]
    const float* gts    = (const float*)d_in[2];   // [1,M,4]
    const int*   labels = (const int*)  d_in[3];   // [1,M]
    int N = in_sizes[1] / 4;
    int M = in_sizes[2] / 4;

    char* ws = (char*)d_ws;
    int*     cnt    = (int*)    (ws + WS_CNT);
    int*     grpPos = (int*)    (ws + WS_GRPPOS);
    int*     grpNeg = (int*)    (ws + WS_GRPNEG);
    int16_t* bestgt = (int16_t*)(ws + WS_BESTGT);
    uint8_t* key    = (uint8_t*)(ws + WS_KEY);

    int nblk    = (N + 127) / 128;
    int ngroups = (N + 63) / 64;

    float* outD = (float*)d_out;          // [1,256,4]
    float* outH = outD + RPI * 4;         // [1,256,91]

    hipMemsetAsync(cnt, 0, sizeof(int), stream);    // arrival counter = 0 each launch
    ptl_fused<<<nblk, 256, 0, stream>>>(rois, gts, labels, N, M,
                                        key, bestgt, grpPos, grpNeg, cnt,
                                        outD, outH, ngroups);
}

// Round 5
// 48.881 us; speedup vs baseline: 2.6628x; 2.6628x over previous
//
#include <hip/hip_runtime.h>
#include <cstdint>

// ---------------- problem constants ----------------
static constexpr int RPI    = 256;   // ROIS_PER_IMAGE
static constexpr int MAXPOS = 64;    // round(256*0.25)
static constexpr int MAXG   = 4096;  // max 64-ROI groups (N <= 262144)

// ---------------- workspace layout (bytes) ----------------
static constexpr size_t WS_GRPPOS = 0;
static constexpr size_t WS_GRPNEG = WS_GRPPOS + (size_t)MAXG * 4;
static constexpr size_t WS_BESTGT = WS_GRPNEG + (size_t)MAXG * 4;       // int16 per ROI
static constexpr size_t WS_KEY    = WS_BESTGT + (size_t)262144 * 2;     // uint8 per ROI

// ---------------- kernel 1: IoU argmax + classify + per-group counts -------------
// Block = 64 threads = 1 wave = 1 ROI/thread. NO LDS, NO barriers. GT box is
// read with a wave-uniform index -> compiler emits s_load_dwordx4 (scalar
// pipe + K$; 3.2KB stays hot). Rational argmax tracking (bi, c1):
//   r_c > r_b  <=>  I_c*c1_b > bi_b*S_c,   S = (areaA+eps)+areaB
// (comparator is a monotone proxy; near-ulp ties only). Final merged value is
// RECOMPUTED in exact reference op order for the winning j, then divided once
// (IEEE f32) -> threshold compares bit-exact given correct argmax (this
// scheme passed with absmax 0 in R2/R3).
__global__ __launch_bounds__(64) void iou_kernel(
    const float* __restrict__ rois, const float* __restrict__ gts,
    int N, int M,
    uint8_t* __restrict__ key, int16_t* __restrict__ bestgt,
    int* __restrict__ grpPos, int* __restrict__ grpNeg)
{
#pragma clang fp contract(off)
    const int l = threadIdx.x;
    const int r = blockIdx.x * 64 + l;
    const float4 zb = make_float4(0.f, 0.f, 0.f, 0.f);
    float4 b = (r < N) ? ((const float4*)rois)[r] : zb;
    float aA  = (b.z - b.x) * (b.w - b.y);   // ref op order (used in exact recompute)
    float aAe = aA + 1e-7f;                  // comparator-side only

    float bi = -1.f, c1 = 0.f;               // first j always wins (0 > -S)
    int   bj = 0;
#pragma unroll 4
    for (int j = 0; j < M; ++j) {
        float4 g = ((const float4*)gts)[j]; // uniform index -> s_load_dwordx4
        float gh = g.z - g.x, gw = g.w - g.y;
        float ab = gh * gw;
        float ih = fmaxf(fminf(b.z, g.z) - fmaxf(b.x, g.x), 0.f);
        float iw = fmaxf(fminf(b.w, g.w) - fmaxf(b.y, g.y), 0.f);
        float inter = ih * iw;
        float S = aAe + ab;
        bool  s = (inter * c1) > (bi * S);
        bi = s ? inter : bi;  c1 = s ? S : c1;  bj = s ? j : bj;
    }

    int kk = 2;
    if (r < N) {
        // exact recompute of merged = iou(r, bj) in reference op order
        float4 g  = ((const float4*)gts)[bj];        // divergent vector load (hot)
        float  ab = (g.z - g.x) * (g.w - g.y);
        float ih = fmaxf(fminf(b.z, g.z) - fmaxf(b.x, g.x), 0.f);
        float iw = fmaxf(fminf(b.w, g.w) - fmaxf(b.y, g.y), 0.f);
        float inter = ih * iw;
        float u1 = ((aA + ab) - inter) + 1e-7f;
        float q  = inter / u1;                       // the ONLY division
        kk = (q > 0.5f) ? 0 : ((q < 0.5f && q > 0.1f) ? 1 : 2);
        key[r]    = (uint8_t)kk;
        bestgt[r] = (int16_t)bj;
    }

    unsigned long long mp = __ballot(kk == 0);
    unsigned long long mn = __ballot(kk == 1);
    if (l == 0) {
        grpPos[blockIdx.x] = __popcll(mp);
        grpNeg[blockIdx.x] = __popcll(mn);
    }
}

// ---------------- kernel 2: totals + first-k select + emit (single block) --------
// No full prefix scan: only TOTALS are needed (for quotas); selection is a
// serial group walk by wave 0 with next-group prefetch and early exit (quotas
// fill within the first ~100 groups on this data; R3 validated the pattern).
__global__ __launch_bounds__(256) void finish_kernel(
    const float* __restrict__ rois, const float* __restrict__ gts,
    const int* __restrict__ labels,
    const uint8_t* __restrict__ key, const int16_t* __restrict__ bestgt,
    const int* __restrict__ grpPos, const int* __restrict__ grpNeg,
    float* __restrict__ outD, float* __restrict__ outH,
    int N, int ngroups)
{
#pragma clang fp contract(off)
    __shared__ int redP[4], redN[4];
    __shared__ int slot[RPI], slab[RPI];
    __shared__ int s_tp, s_tn;

    const int tid = threadIdx.x, w = tid >> 6, l = tid & 63;

    // ---- totals (sum reduction only) ----
    int sumP = 0, sumN = 0;
    for (int g = tid; g < ngroups; g += 256) { sumP += grpPos[g]; sumN += grpNeg[g]; }
#pragma unroll
    for (int o = 32; o > 0; o >>= 1) {
        sumP += __shfl_down(sumP, o);
        sumN += __shfl_down(sumN, o);
    }
    if (l == 0) { redP[w] = sumP; redN[w] = sumN; }
    if (tid < RPI) slot[tid] = -1;
    __syncthreads();
    if (tid == 0) {
        int totP = redP[0] + redP[1] + redP[2] + redP[3];
        int totN = redN[0] + redN[1] + redN[2] + redN[3];
        int tp  = totP < MAXPOS ? totP : MAXPOS;
        int rem = RPI - tp;
        s_tp = tp;
        s_tn = totN < rem ? totN : rem;
    }
    __syncthreads();
    const int tp = s_tp, tn = s_tn;

    // ---- select: wave 0 walks groups in order, prefetching next group ----
    if (w == 0) {
        int cp = 0, cn = 0;
        int kc = (l < N) ? (int)key[l] : 2;           // group 0 prefetched
        for (int g = 0; g < ngroups && (cp < tp || cn < tn); ++g) {
            int i2 = (g + 1) * 64 + l;
            int kn = (g + 1 < ngroups && i2 < N) ? (int)key[i2] : 2;
            unsigned long long mp = __ballot(kc == 0);
            unsigned long long mn = __ballot(kc == 1);
            unsigned long long lt = (1ull << l) - 1ull;
            int i = g * 64 + l;
            if (kc == 0) {
                int rr = cp + __popcll(mp & lt);
                if (rr < tp) slot[rr] = i;
            } else if (kc == 1) {
                int rr = cn + __popcll(mn & lt);
                if (rr < tn) slot[tp + rr] = i;
            }
            cp += __popcll(mp); cn += __popcll(mn);
            kc = kn;
        }
    }
    __syncthreads();

    // ---- emit: deltas + label per row (256 threads = 256 rows) ----
    {
        int  roi   = slot[tid];
        bool valid = roi >= 0;
        bool ispos = valid && (tid < tp);
        float d0 = 0.f, d1 = 0.f, d2 = 0.f, d3 = 0.f;
        int lab = valid ? 0 : -1;                     // -1 => all-zero one-hot row
        if (ispos) {
            int gi    = (int)bestgt[roi];
            float4 b  = ((const float4*)rois)[roi];
            float4 gb = ((const float4*)gts)[gi];
            lab = labels[gi];
            float bh  = b.z - b.x,  bw  = b.w - b.y;
            float bcy = b.x + 0.5f * bh, bcx = b.y + 0.5f * bw;
            float gh  = gb.z - gb.x, gw  = gb.w - gb.y;
            float gcy = gb.x + 0.5f * gh, gcx = gb.y + 0.5f * gw;
            float bhs = (bh == 0.f) ? 1.f : bh;
            float bws = (bw == 0.f) ? 1.f : bw;
            float ghs = (gh <= 0.f) ? 1.f : gh;
            float gws = (gw <= 0.f) ? 1.f : gw;
            float dy = (gh == 0.f) ? 0.f : (gcy - bcy) / bhs;
            float dx = (gw == 0.f) ? 0.f : (gcx - bcx) / bws;
            float dh = (gh == 0.f) ? 0.f : logf(ghs / bhs);
            float dw = (gw == 0.f) ? 0.f : logf(gws / bws);
            d0 = dy / 0.1f; d1 = dx / 0.1f; d2 = dh / 0.2f; d3 = dw / 0.2f;
        }
        slab[tid] = lab;
        ((float4*)outD)[tid] = make_float4(d0, d1, d2, d3);
    }
    __syncthreads();

    // ---- one-hot: coalesced, div-free index walk (91 iters of 256) ----
    {
        int rr = tid / 91, cc = tid - rr * 91;
        for (int it = 0; it < 91; ++it) {
            outH[rr * 91 + cc] = (cc == slab[rr]) ? 1.0f : 0.0f;
            cc += 74; rr += 2;                        // advance by 256 elements
            if (cc >= 91) { cc -= 91; ++rr; }
        }
    }
}

// ---------------- host launcher ----------------
extern "C" void kernel_launch(void* const* d_in, const int* in_sizes, int n_in,
                              void* d_out, int out_size, void* d_ws, size_t ws_size,
                              hipStream_t stream) {
    const float* rois   = (const float*)d_in[1];   // [1,N,4]
    const float* gts    = (const float*)d_in[2];   // [1,M,4]
    const int*   labels = (const int*)  d_in[3];   // [1,M]
    int N = in_sizes[1] / 4;
    int M = in_sizes[2] / 4;

    char* ws = (char*)d_ws;
    int*     grpPos = (int*)    (ws + WS_GRPPOS);
    int*     grpNeg = (int*)    (ws + WS_GRPNEG);
    int16_t* bestgt = (int16_t*)(ws + WS_BESTGT);
    uint8_t* key    = (uint8_t*)(ws + WS_KEY);

    int ngroups = (N + 63) / 64;                   // == grid of iou_kernel

    iou_kernel<<<ngroups, 64, 0, stream>>>(rois, gts, N, M, key, bestgt, grpPos, grpNeg);

    float* outD = (float*)d_out;          // [1,256,4]
    float* outH = outD + RPI * 4;         // [1,256,91]
    finish_kernel<<<1, 256, 0, stream>>>(rois, gts, labels, key, bestgt,
                                         grpPos, grpNeg, outD, outH, N, ngroups);
}

// Round 6
// 39.877 us; speedup vs baseline: 3.2641x; 1.2258x over previous
//
#include <hip/hip_runtime.h>
#include <cstdint>

// ---------------- problem constants ----------------
static constexpr int RPI    = 256;   // ROIS_PER_IMAGE
static constexpr int MAXPOS = 64;    // round(256*0.25)
static constexpr int MAX_GT = 256;   // LDS capacity for gt boxes (M=200)
static constexpr int MAXG   = 4096;  // max 64-ROI groups (N <= 262144)

// ---------------- workspace layout (bytes) ----------------
static constexpr size_t WS_GRPPK  = 0;                                  // packed (pos<<16|neg)
static constexpr size_t WS_BESTGT = WS_GRPPK + (size_t)MAXG * 4;        // int16 per ROI
static constexpr size_t WS_KEY    = WS_BESTGT + (size_t)262144 * 2;     // uint8 per ROI

// ---------------- kernel 1: IoU argmax + classify + per-group counts -------------
// R3-proven structure: block = 256 thr = 4 waves, owns 128 ROIs (2/lane);
// each wave processes all 128 ROIs against ITS quarter of the GT list.
// NEW: software-pipelined LDS reads — (g, abe) for iteration j+1 are loaded
// into registers BEFORE computing iteration j, hiding the ~120-cyc ds_read
// latency under the 32 VALU insts of the current iteration.
// Rational argmax tracking (bi, c1): r_c > r_b  <=>  I_c*c1_b > bi_b*S_c.
// Final merged value RECOMPUTED in exact reference op order for the winning
// j, ONE IEEE divide -> threshold compares bit-exact (absmax 0 in R2/R3/R5).
__global__ __launch_bounds__(256) void iou_kernel(
    const float* __restrict__ rois, const float* __restrict__ gts,
    int N, int M,
    uint8_t* __restrict__ key, int16_t* __restrict__ bestgt,
    int* __restrict__ grpPk)
{
#pragma clang fp contract(off)
    __shared__ float4 sgt[MAX_GT];
    __shared__ float  sarea[MAX_GT];     // exact area (recompute path)
    __shared__ float  sabe[MAX_GT];      // area + 1e-7 (comparator side)
    __shared__ float  sbi[4][128];
    __shared__ float  sc1[4][128];
    __shared__ short  sbj[4][128];

    const int tid = threadIdx.x;
    for (int j = tid; j < M; j += 256) {
        float4 g = ((const float4*)gts)[j];
        sgt[j] = g;
        float a = (g.z - g.x) * (g.w - g.y);   // ref op order
        sarea[j] = a;
        sabe[j]  = a + 1e-7f;
    }
    __syncthreads();

    const int w = tid >> 6, l = tid & 63;
    const int base = blockIdx.x * 128;
    const int r0 = base + l, r1 = r0 + 64;
    const float4 zb = make_float4(0.f, 0.f, 0.f, 0.f);
    float4 b0 = (r0 < N) ? ((const float4*)rois)[r0] : zb;
    float4 b1 = (r1 < N) ? ((const float4*)rois)[r1] : zb;
    float aA0 = (b0.z - b0.x) * (b0.w - b0.y);
    float aA1 = (b1.z - b1.x) * (b1.w - b1.y);

    const int seglen = (M + 3) >> 2;
    const int j0 = w * seglen, j1 = min(M, j0 + seglen);

    float bi0 = -1.f, c10 = 0.f, bi1 = -1.f, c11 = 0.f;   // first j always wins
    int   bj0 = j0,   bj1 = j0;

    // software pipeline: current (g, ae) in regs; prefetch next each iter
    float4 g  = sgt[j0];                 // arrays sized 256 -> j+1 read in-bounds
    float  ae = sabe[j0];
#pragma unroll 2
    for (int j = j0; j < j1; ++j) {
        float4 gn = sgt[j + 1];          // issued before compute; latency hidden
        float  an = sabe[j + 1];
        {
            float ih = fmaxf(fminf(b0.z, g.z) - fmaxf(b0.x, g.x), 0.f);
            float iw = fmaxf(fminf(b0.w, g.w) - fmaxf(b0.y, g.y), 0.f);
            float inter = ih * iw;
            float S = aA0 + ae;
            bool  s = (inter * c10) > (bi0 * S);
            bi0 = s ? inter : bi0;  c10 = s ? S : c10;  bj0 = s ? j : bj0;
        }
        {
            float ih = fmaxf(fminf(b1.z, g.z) - fmaxf(b1.x, g.x), 0.f);
            float iw = fmaxf(fminf(b1.w, g.w) - fmaxf(b1.y, g.y), 0.f);
            float inter = ih * iw;
            float S = aA1 + ae;
            bool  s = (inter * c11) > (bi1 * S);
            bi1 = s ? inter : bi1;  c11 = s ? S : c11;  bj1 = s ? j : bj1;
        }
        g = gn; ae = an;
    }
    sbi[w][l]      = bi0;  sc1[w][l]      = c10;  sbj[w][l]      = (short)bj0;
    sbi[w][64 + l] = bi1;  sc1[w][64 + l] = c11;  sbj[w][64 + l] = (short)bj1;
    __syncthreads();

    // ---- merge segment partials (order keeps first-occurrence argmax) ----
    if (tid < 128) {
        float BI = sbi[0][tid], C1 = sc1[0][tid];
        int   BJ = (int)sbj[0][tid];
#pragma unroll
        for (int s2 = 1; s2 < 4; ++s2) {
            float ci = sbi[s2][tid], cc = sc1[s2][tid];
            bool sel = (ci * C1) > (BI * cc);
            BI = sel ? ci : BI;  C1 = sel ? cc : C1;
            BJ = sel ? (int)sbj[s2][tid] : BJ;
        }
        float4 bb = (tid < 64) ? b0 : b1;   // thread tid holds box of ROI base+tid
        float  aa = (tid < 64) ? aA0 : aA1;
        int r = base + tid;
        int kk = 2;
        if (r < N) {
            // exact recompute of merged = iou(r, BJ) in reference op order
            float4 gg = sgt[BJ];
            float  ab = sarea[BJ];
            float ih = fmaxf(fminf(bb.z, gg.z) - fmaxf(bb.x, gg.x), 0.f);
            float iw = fmaxf(fminf(bb.w, gg.w) - fmaxf(bb.y, gg.y), 0.f);
            float inter = ih * iw;
            float u1 = ((aa + ab) - inter) + 1e-7f;
            float q  = inter / u1;             // the ONLY division
            kk = (q > 0.5f) ? 0 : ((q < 0.5f && q > 0.1f) ? 1 : 2);
            key[r]    = (uint8_t)kk;
            bestgt[r] = (int16_t)BJ;
        }
        unsigned long long mp = __ballot(kk == 0);
        unsigned long long mn = __ballot(kk == 1);
        if (l == 0)
            grpPk[blockIdx.x * 2 + w] = (__popcll(mp) << 16) | __popcll(mn);
    }
}

// ---------------- kernel 2: totals + first-k select + emit (single block) --------
__global__ __launch_bounds__(1024) void finish_kernel(
    const float* __restrict__ rois, const float* __restrict__ gts,
    const int* __restrict__ labels,
    const uint8_t* __restrict__ key, const int16_t* __restrict__ bestgt,
    const int* __restrict__ grpPk,
    float* __restrict__ outD, float* __restrict__ outH,
    int N, int ngroups)
{
#pragma clang fp contract(off)
    __shared__ int redP[16], redN[16];
    __shared__ int slot[RPI], slab[RPI];
    __shared__ int s_tp, s_tn;

    const int tid = threadIdx.x, w = tid >> 6, l = tid & 63;

    // ---- totals (packed counts, sum reduction) ----
    int sumP = 0, sumN = 0;
    for (int g = tid; g < ngroups; g += 1024) {
        int v = grpPk[g];
        sumP += v >> 16;
        sumN += v & 0xFFFF;
    }
#pragma unroll
    for (int o = 32; o > 0; o >>= 1) {
        sumP += __shfl_down(sumP, o);
        sumN += __shfl_down(sumN, o);
    }
    if (l == 0) { redP[w] = sumP; redN[w] = sumN; }
    if (tid < RPI) slot[tid] = -1;
    __syncthreads();
    if (tid == 0) {
        int totP = 0, totN = 0;
#pragma unroll
        for (int x = 0; x < 16; ++x) { totP += redP[x]; totN += redN[x]; }
        int tp  = totP < MAXPOS ? totP : MAXPOS;
        int rem = RPI - tp;
        s_tp = tp;
        s_tn = totN < rem ? totN : rem;
    }
    __syncthreads();
    const int tp = s_tp, tn = s_tn;

    // ---- select: wave 0 walks groups in order, prefetching next group ----
    if (w == 0) {
        int cp = 0, cn = 0;
        int kc = (l < N) ? (int)key[l] : 2;           // group 0 prefetched
        for (int g = 0; g < ngroups && (cp < tp || cn < tn); ++g) {
            int i2 = (g + 1) * 64 + l;
            int kn = (g + 1 < ngroups && i2 < N) ? (int)key[i2] : 2;
            unsigned long long mp = __ballot(kc == 0);
            unsigned long long mn = __ballot(kc == 1);
            unsigned long long lt = (1ull << l) - 1ull;
            int i = g * 64 + l;
            if (kc == 0) {
                int rr = cp + __popcll(mp & lt);
                if (rr < tp) slot[rr] = i;
            } else if (kc == 1) {
                int rr = cn + __popcll(mn & lt);
                if (rr < tn) slot[tp + rr] = i;
            }
            cp += __popcll(mp); cn += __popcll(mn);
            kc = kn;
        }
    }
    __syncthreads();

    // ---- emit: deltas + label per row (first 256 threads = 256 rows) ----
    if (tid < RPI) {
        int  roi   = slot[tid];
        bool valid = roi >= 0;
        bool ispos = valid && (tid < tp);
        float d0 = 0.f, d1 = 0.f, d2 = 0.f, d3 = 0.f;
        int lab = valid ? 0 : -1;                     // -1 => all-zero one-hot row
        if (ispos) {
            int gi    = (int)bestgt[roi];
            float4 b  = ((const float4*)rois)[roi];
            float4 gb = ((const float4*)gts)[gi];
            lab = labels[gi];
            float bh  = b.z - b.x,  bw  = b.w - b.y;
            float bcy = b.x + 0.5f * bh, bcx = b.y + 0.5f * bw;
            float gh  = gb.z - gb.x, gw  = gb.w - gb.y;
            float gcy = gb.x + 0.5f * gh, gcx = gb.y + 0.5f * gw;
            float bhs = (bh == 0.f) ? 1.f : bh;
            float bws = (bw == 0.f) ? 1.f : bw;
            float ghs = (gh <= 0.f) ? 1.f : gh;
            float gws = (gw <= 0.f) ? 1.f : gw;
            float dy = (gh == 0.f) ? 0.f : (gcy - bcy) / bhs;
            float dx = (gw == 0.f) ? 0.f : (gcx - bcx) / bws;
            float dh = (gh == 0.f) ? 0.f : logf(ghs / bhs);
            float dw = (gw == 0.f) ? 0.f : logf(gws / bws);
            d0 = dy / 0.1f; d1 = dx / 0.1f; d2 = dh / 0.2f; d3 = dw / 0.2f;
        }
        slab[tid] = lab;
        ((float4*)outD)[tid] = make_float4(d0, d1, d2, d3);
    }
    __syncthreads();

    // ---- one-hot: coalesced over 256*91, 1024 threads ----
    for (int idx = tid; idx < RPI * 91; idx += 1024) {
        int rr = idx / 91;                 // compiler magic-mul, cheap
        int cc = idx - rr * 91;
        outH[idx] = (cc == slab[rr]) ? 1.0f : 0.0f;
    }
}

// ---------------- host launcher ----------------
extern "C" void kernel_launch(void* const* d_in, const int* in_sizes, int n_in,
                              void* d_out, int out_size, void* d_ws, size_t ws_size,
                              hipStream_t stream) {
    const float* rois   = (const float*)d_in[1];   // [1,N,4]
    const float* gts    = (const float*)d_in[2];   // [1,M,4]
    const int*   labels = (const int*)  d_in[3];   // [1,M]
    int N = in_sizes[1] / 4;
    int M = in_sizes[2] / 4;

    char* ws = (char*)d_ws;
    int*     grpPk  = (int*)    (ws + WS_GRPPK);
    int16_t* bestgt = (int16_t*)(ws + WS_BESTGT);
    uint8_t* key    = (uint8_t*)(ws + WS_KEY);

    int nblk    = (N + 127) / 128;
    int ngroups = (N + 63) / 64;

    iou_kernel<<<nblk, 256, 0, stream>>>(rois, gts, N, M, key, bestgt, grpPk);

    float* outD = (float*)d_out;          // [1,256,4]
    float* outH = outD + RPI * 4;         // [1,256,91]
    finish_kernel<<<1, 1024, 0, stream>>>(rois, gts, labels, key, bestgt,
                                          grpPk, outD, outH, N, ngroups);
}

// Round 7
// 24.688 us; speedup vs baseline: 5.2722x; 1.6152x over previous
//
#include <hip/hip_runtime.h>
#include <cstdint>

// ---------------- problem constants ----------------
static constexpr int RPI    = 256;   // ROIS_PER_IMAGE
static constexpr int MAXPOS = 64;    // round(256*0.25)
static constexpr int MAX_GT = 256;   // LDS capacity for gt boxes (M=200)
static constexpr int MAXG   = 4096;  // max 64-ROI groups (N <= 262144)
static constexpr int NBLK_A = 32;    // phase-A blocks (128 ROIs each -> 64 groups)

// ---------------- workspace layout (bytes) ----------------
static constexpr size_t WS_FLAG   = 0;                                  // int: fast-path flag
static constexpr size_t WS_TOTQ   = 8;                                  // 2 ints: tp, tn (fast path)
static constexpr size_t WS_GRPPK  = 64;                                 // packed (pos<<16|neg)
static constexpr size_t WS_BESTGT = WS_GRPPK + (size_t)MAXG * 4;        // int16 per ROI
static constexpr size_t WS_KEY    = WS_BESTGT + (size_t)262144 * 2;     // uint8 per ROI

// ---------------- kernel 1: IoU argmax + classify + per-group counts -------------
// R3/R6-proven body (absmax 0). Block = 256 thr = 4 waves, owns 128 ROIs
// (2/lane); each wave handles ITS quarter of the GT list; partials merged in
// segment order. Rational argmax tracking (bi,c1): r_c > r_b <=> I_c*c1_b >
// bi_b*S_c. Winner's IoU RECOMPUTED in exact reference op order, ONE IEEE
// divide -> thresholds bit-exact. NEW: optional skip flag (phase C early-exit)
// and block offset (phase C starts after phase A's blocks).
__global__ __launch_bounds__(256) void iou_kernel(
    const float* __restrict__ rois, const float* __restrict__ gts,
    int N, int M,
    uint8_t* __restrict__ key, int16_t* __restrict__ bestgt,
    int* __restrict__ grpPk, const int* __restrict__ skip, int bofs)
{
#pragma clang fp contract(off)
    if (skip && skip[0]) return;          // fast path: quotas proven filled

    __shared__ float4 sgt[MAX_GT];
    __shared__ float  sarea[MAX_GT];     // exact area (recompute path)
    __shared__ float  sabe[MAX_GT];      // area + 1e-7 (comparator side)
    __shared__ float  sbi[4][128];
    __shared__ float  sc1[4][128];
    __shared__ short  sbj[4][128];

    const int tid = threadIdx.x;
    for (int j = tid; j < M; j += 256) {
        float4 g = ((const float4*)gts)[j];
        sgt[j] = g;
        float a = (g.z - g.x) * (g.w - g.y);   // ref op order
        sarea[j] = a;
        sabe[j]  = a + 1e-7f;
    }
    __syncthreads();

    const int w = tid >> 6, l = tid & 63;
    const int base = (blockIdx.x + bofs) * 128;
    const int r0 = base + l, r1 = r0 + 64;
    const float4 zb = make_float4(0.f, 0.f, 0.f, 0.f);
    float4 b0 = (r0 < N) ? ((const float4*)rois)[r0] : zb;
    float4 b1 = (r1 < N) ? ((const float4*)rois)[r1] : zb;
    float aA0 = (b0.z - b0.x) * (b0.w - b0.y);
    float aA1 = (b1.z - b1.x) * (b1.w - b1.y);

    const int seglen = (M + 3) >> 2;
    const int j0 = w * seglen, j1 = min(M, j0 + seglen);

    float bi0 = -1.f, c10 = 0.f, bi1 = -1.f, c11 = 0.f;   // first j always wins
    int   bj0 = j0,   bj1 = j0;

    float4 g  = sgt[j0];                 // sized-256 arrays: j+1 read in-bounds
    float  ae = sabe[j0];
#pragma unroll 2
    for (int j = j0; j < j1; ++j) {
        float4 gn = sgt[j + 1];          // register prefetch
        float  an = sabe[j + 1];
        {
            float ih = fmaxf(fminf(b0.z, g.z) - fmaxf(b0.x, g.x), 0.f);
            float iw = fmaxf(fminf(b0.w, g.w) - fmaxf(b0.y, g.y), 0.f);
            float inter = ih * iw;
            float S = aA0 + ae;
            bool  s = (inter * c10) > (bi0 * S);
            bi0 = s ? inter : bi0;  c10 = s ? S : c10;  bj0 = s ? j : bj0;
        }
        {
            float ih = fmaxf(fminf(b1.z, g.z) - fmaxf(b1.x, g.x), 0.f);
            float iw = fmaxf(fminf(b1.w, g.w) - fmaxf(b1.y, g.y), 0.f);
            float inter = ih * iw;
            float S = aA1 + ae;
            bool  s = (inter * c11) > (bi1 * S);
            bi1 = s ? inter : bi1;  c11 = s ? S : c11;  bj1 = s ? j : bj1;
        }
        g = gn; ae = an;
    }
    sbi[w][l]      = bi0;  sc1[w][l]      = c10;  sbj[w][l]      = (short)bj0;
    sbi[w][64 + l] = bi1;  sc1[w][64 + l] = c11;  sbj[w][64 + l] = (short)bj1;
    __syncthreads();

    if (tid < 128) {
        float BI = sbi[0][tid], C1 = sc1[0][tid];
        int   BJ = (int)sbj[0][tid];
#pragma unroll
        for (int s2 = 1; s2 < 4; ++s2) {
            float ci = sbi[s2][tid], cc = sc1[s2][tid];
            bool sel = (ci * C1) > (BI * cc);
            BI = sel ? ci : BI;  C1 = sel ? cc : C1;
            BJ = sel ? (int)sbj[s2][tid] : BJ;
        }
        float4 bb = (tid < 64) ? b0 : b1;   // thread tid holds box of ROI base+tid
        float  aa = (tid < 64) ? aA0 : aA1;
        int r = base + tid;
        int kk = 2;
        if (r < N) {
            float4 gg = sgt[BJ];
            float  ab = sarea[BJ];
            float ih = fmaxf(fminf(bb.z, gg.z) - fmaxf(bb.x, gg.x), 0.f);
            float iw = fmaxf(fminf(bb.w, gg.w) - fmaxf(bb.y, gg.y), 0.f);
            float inter = ih * iw;
            float u1 = ((aa + ab) - inter) + 1e-7f;   // exact ref op order
            float q  = inter / u1;                    // the ONLY division
            kk = (q > 0.5f) ? 0 : ((q < 0.5f && q > 0.1f) ? 1 : 2);
            key[r]    = (uint8_t)kk;
            bestgt[r] = (int16_t)BJ;
        }
        unsigned long long mp = __ballot(kk == 0);
        unsigned long long mn = __ballot(kk == 1);
        if (l == 0)
            grpPk[(blockIdx.x + bofs) * 2 + w] = (__popcll(mp) << 16) | __popcll(mn);
    }
}

// ---------------- kernel 2: quota check over the first kgrp groups ---------------
// If the prefix already holds >= MAXPOS positives and >= RPI-MAXPOS negatives,
// then tp=MAXPOS, tn=RPI-MAXPOS exactly (min caps saturate) and every selected
// ROI is in the prefix -> the remaining ROIs cannot affect the output.
__global__ __launch_bounds__(64) void quota_kernel(
    const int* __restrict__ grpPk, int kgrp, int* __restrict__ flag, int* __restrict__ totq)
{
    const int l = threadIdx.x;
    int v = (l < kgrp) ? grpPk[l] : 0;
    int p = v >> 16, n = v & 0xFFFF;
#pragma unroll
    for (int o = 1; o < 64; o <<= 1) {
        p += __shfl_xor(p, o);
        n += __shfl_xor(n, o);
    }
    if (l == 0) {
        flag[0] = (p >= MAXPOS && n >= RPI - MAXPOS) ? 1 : 0;
        totq[0] = MAXPOS;
        totq[1] = RPI - MAXPOS;
    }
}

// ---------------- kernel 3: totals + first-k select + emit (single block) --------
__global__ __launch_bounds__(1024) void finish_kernel(
    const float* __restrict__ rois, const float* __restrict__ gts,
    const int* __restrict__ labels,
    const uint8_t* __restrict__ key, const int16_t* __restrict__ bestgt,
    const int* __restrict__ grpPk, const int* __restrict__ flag,
    const int* __restrict__ totq,
    float* __restrict__ outD, float* __restrict__ outH,
    int N, int ngroups)
{
#pragma clang fp contract(off)
    __shared__ int redP[16], redN[16];
    __shared__ int slot[RPI], slab[RPI];
    __shared__ int s_tp, s_tn;

    const int tid = threadIdx.x, w = tid >> 6, l = tid & 63;
    const int fast = flag[0];

    if (tid < RPI) slot[tid] = -1;
    if (fast) {
        if (tid == 0) { s_tp = totq[0]; s_tn = totq[1]; }
    } else {
        // ---- totals (packed counts, sum reduction over all groups) ----
        int sumP = 0, sumN = 0;
        for (int g = tid; g < ngroups; g += 1024) {
            int v = grpPk[g];
            sumP += v >> 16;
            sumN += v & 0xFFFF;
        }
#pragma unroll
        for (int o = 32; o > 0; o >>= 1) {
            sumP += __shfl_down(sumP, o);
            sumN += __shfl_down(sumN, o);
        }
        if (l == 0) { redP[w] = sumP; redN[w] = sumN; }
        __syncthreads();
        if (tid == 0) {
            int totP = 0, totN = 0;
#pragma unroll
            for (int x = 0; x < 16; ++x) { totP += redP[x]; totN += redN[x]; }
            int tp  = totP < MAXPOS ? totP : MAXPOS;
            int rem = RPI - tp;
            s_tp = tp;
            s_tn = totN < rem ? totN : rem;
        }
    }
    __syncthreads();
    const int tp = s_tp, tn = s_tn;

    // ---- select: wave 0 walks groups in order, prefetching next group ----
    if (w == 0) {
        int cp = 0, cn = 0;
        int kc = (l < N) ? (int)key[l] : 2;           // group 0 prefetched
        for (int g = 0; g < ngroups && (cp < tp || cn < tn); ++g) {
            int i2 = (g + 1) * 64 + l;
            int kn = (g + 1 < ngroups && i2 < N) ? (int)key[i2] : 2;
            unsigned long long mp = __ballot(kc == 0);
            unsigned long long mn = __ballot(kc == 1);
            unsigned long long lt = (1ull << l) - 1ull;
            int i = g * 64 + l;
            if (kc == 0) {
                int rr = cp + __popcll(mp & lt);
                if (rr < tp) slot[rr] = i;
            } else if (kc == 1) {
                int rr = cn + __popcll(mn & lt);
                if (rr < tn) slot[tp + rr] = i;
            }
            cp += __popcll(mp); cn += __popcll(mn);
            kc = kn;
        }
    }
    __syncthreads();

    // ---- emit: deltas + label per row (first 256 threads = 256 rows) ----
    if (tid < RPI) {
        int  roi   = slot[tid];
        bool valid = roi >= 0;
        bool ispos = valid && (tid < tp);
        float d0 = 0.f, d1 = 0.f, d2 = 0.f, d3 = 0.f;
        int lab = valid ? 0 : -1;                     // -1 => all-zero one-hot row
        if (ispos) {
            int gi    = (int)bestgt[roi];
            float4 b  = ((const float4*)rois)[roi];
            float4 gb = ((const float4*)gts)[gi];
            lab = labels[gi];
            float bh  = b.z - b.x,  bw  = b.w - b.y;
            float bcy = b.x + 0.5f * bh, bcx = b.y + 0.5f * bw;
            float gh  = gb.z - gb.x, gw  = gb.w - gb.y;
            float gcy = gb.x + 0.5f * gh, gcx = gb.y + 0.5f * gw;
            float bhs = (bh == 0.f) ? 1.f : bh;
            float bws = (bw == 0.f) ? 1.f : bw;
            float ghs = (gh <= 0.f) ? 1.f : gh;
            float gws = (gw <= 0.f) ? 1.f : gw;
            float dy = (gh == 0.f) ? 0.f : (gcy - bcy) / bhs;
            float dx = (gw == 0.f) ? 0.f : (gcx - bcx) / bws;
            float dh = (gh == 0.f) ? 0.f : logf(ghs / bhs);
            float dw = (gw == 0.f) ? 0.f : logf(gws / bws);
            d0 = dy / 0.1f; d1 = dx / 0.1f; d2 = dh / 0.2f; d3 = dw / 0.2f;
        }
        slab[tid] = lab;
        ((float4*)outD)[tid] = make_float4(d0, d1, d2, d3);
    }
    __syncthreads();

    // ---- one-hot: coalesced over 256*91, 1024 threads ----
    for (int idx = tid; idx < RPI * 91; idx += 1024) {
        int rr = idx / 91;
        int cc = idx - rr * 91;
        outH[idx] = (cc == slab[rr]) ? 1.0f : 0.0f;
    }
}

// ---------------- host launcher ----------------
extern "C" void kernel_launch(void* const* d_in, const int* in_sizes, int n_in,
                              void* d_out, int out_size, void* d_ws, size_t ws_size,
                              hipStream_t stream) {
    const float* rois   = (const float*)d_in[1];   // [1,N,4]
    const float* gts    = (const float*)d_in[2];   // [1,M,4]
    const int*   labels = (const int*)  d_in[3];   // [1,M]
    int N = in_sizes[1] / 4;
    int M = in_sizes[2] / 4;

    char* ws = (char*)d_ws;
    int*     flag   = (int*)    (ws + WS_FLAG);
    int*     totq   = (int*)    (ws + WS_TOTQ);
    int*     grpPk  = (int*)    (ws + WS_GRPPK);
    int16_t* bestgt = (int16_t*)(ws + WS_BESTGT);
    uint8_t* key    = (uint8_t*)(ws + WS_KEY);

    int nblk    = (N + 127) / 128;
    int ngroups = (N + 63) / 64;
    int nblkA   = nblk < NBLK_A ? nblk : NBLK_A;
    int kgrp    = ngroups < 2 * nblkA ? ngroups : 2 * nblkA;
    int nblkC   = nblk - nblkA;

    float* outD = (float*)d_out;          // [1,256,4]
    float* outH = outD + RPI * 4;         // [1,256,91]

    // Phase A: exact IoU on the first nblkA*128 ROIs (always runs)
    iou_kernel<<<nblkA, 256, 0, stream>>>(rois, gts, N, M, key, bestgt, grpPk,
                                          nullptr, 0);
    // Phase B: can the prefix alone fill both quotas?
    quota_kernel<<<1, 64, 0, stream>>>(grpPk, kgrp, flag, totq);
    // Phase C: rest of the ROIs; blocks early-exit when flag==1
    if (nblkC > 0)
        iou_kernel<<<nblkC, 256, 0, stream>>>(rois, gts, N, M, key, bestgt, grpPk,
                                              flag, nblkA);
    // Finish: totals (or fast-path quotas) + select + emit
    finish_kernel<<<1, 1024, 0, stream>>>(rois, gts, labels, key, bestgt,
                                          grpPk, flag, totq, outD, outH, N, ngroups);
}